// Round 17
// baseline (415.674 us; speedup 1.0000x reference)
//
#include <hip/hip_runtime.h>
#include <hip/hip_fp16.h>
#include <stdint.h>

// SymmetricQuantLinear: out[m,n] = scale[n] * sum_k x[m,k] * (nib(k,n) - 8)
// Round 17: R16 counted-queue structure + mfma_f32_32x32x16_f16 (fewer,
//   fatter MFMA: 256/tile/CU @8.07cy vs 512 @4.85) + hoisted swizzled
//   ds_read addresses (XOR ks-masks 32/64/96; +4096B imm per m/n block).
//   Staging units, WAITV(4)/(6) queue, 2 barriers/tile: identical to R16.

#define M_DIM 4096
#define K_DIM 4096
#define N_DIM 11008
#define KH    (K_DIM / 2)

#define WS_XH_BYTES  ((size_t)M_DIM * K_DIM * 2)            // 32 MiB

typedef __attribute__((ext_vector_type(8)))  _Float16 f16x8;
typedef __attribute__((ext_vector_type(2)))  _Float16 h2;
typedef __attribute__((ext_vector_type(16))) float f32x16;

__device__ __forceinline__ unsigned pack_f16_pair(float lo, float hi) {
    return __builtin_bit_cast(unsigned, __builtin_amdgcn_cvt_pkrtz(lo, hi));
}

__device__ __forceinline__ unsigned dq_pair(unsigned v) {
    unsigned c = (v & 0xFu) | ((v << 12) & 0x000F0000u) | 0x64006400u;
    h2 r = __builtin_bit_cast(h2, c) + __builtin_bit_cast(h2, 0xE408E408u);
    return __builtin_bit_cast(unsigned, r);
}

__device__ __forceinline__ void gld_lds16(const void* g, void* l) {
    __builtin_amdgcn_global_load_lds(
        (const __attribute__((address_space(1))) unsigned int*)g,
        (__attribute__((address_space(3))) unsigned int*)l,
        16, 0, 0);
}

// ---- Pass 1a: X f32 -> fp16 (exact) ----
__global__ void __launch_bounds__(256) cvt_x_kernel(
    const float* __restrict__ X, unsigned short* __restrict__ Xh)
{
    size_t i = ((size_t)blockIdx.x * 256 + threadIdx.x) * 8;
    float4 a = *(const float4*)(X + i);
    float4 b = *(const float4*)(X + i + 4);
    uint4 o = make_uint4(pack_f16_pair(a.x, a.y), pack_f16_pair(a.z, a.w),
                         pack_f16_pair(b.x, b.y), pack_f16_pair(b.z, b.w));
    *(uint4*)(Xh + i) = o;
}

// ---- Pass 1b: WP [KH][N] -> Wt uint32 [N][KH] ----
__global__ void __launch_bounds__(256) dqt_kernel(
    const int* __restrict__ WP, unsigned* __restrict__ Wt)
{
    __shared__ unsigned Lt[64][65];
    const int t = threadIdx.x;
    const int n0 = blockIdx.x * 64;
    const int r0 = blockIdx.y * 64;
    const int g = t >> 6, l = t & 63;
#pragma unroll
    for (int i = 0; i < 16; ++i) {
        const int r = r0 + g * 16 + i;
        Lt[l][g * 16 + i] = dq_pair((unsigned)WP[(size_t)r * N_DIM + n0 + l]);
    }
    __syncthreads();
    const int nr = t >> 2, sg = t & 3;
    unsigned* dst = Wt + (size_t)(n0 + nr) * KH + r0 + sg * 16;
#pragma unroll
    for (int c = 0; c < 4; ++c) {
        uint4 v = make_uint4(Lt[nr][sg * 16 + c * 4 + 0], Lt[nr][sg * 16 + c * 4 + 1],
                             Lt[nr][sg * 16 + c * 4 + 2], Lt[nr][sg * 16 + c * 4 + 3]);
        *(uint4*)(dst + c * 4) = v;
    }
}

// ---- Pass 2: counted-queue 8-phase fp16 GEMM, 32x32x16 MFMA ----
__global__ void __launch_bounds__(512, 2) qgemm10_kernel(
    const unsigned short* __restrict__ Xh,   // fp16 [M][K]
    const unsigned*       __restrict__ Wt,   // uint32 [N][KH] (fp16 [N][K])
    const float*          __restrict__ WS,   // [N]
    float*                __restrict__ Out)  // f32 [M][N]
{
    __shared__ unsigned short LA[2][2][8192];   // [dbuf][half][128 rows x 64]
    __shared__ unsigned short LB[2][2][8192];   // 128 KB total

    const int t = threadIdx.x;     // 0..511
    const int w = t >> 6;          // wave 0..7
    const int l = t & 63;

    // XCD pairing: xcd owns M-rows {2x,2x+1}, N-major (R14: FETCH 403 MB).
    const int bid = blockIdx.x;                 // 0..687
    const int xcd = bid & 7;
    const int i8  = bid >> 3;                   // 0..85
    const int bx  = i8 >> 1;                    // 0..42
    const int by  = (xcd << 1) | (i8 & 1);      // 0..15
    const int bm0 = by * 256;
    const int bn0 = bx * 256;

    const int wr = w >> 2;         // A half (128 rows)
    const int wc = w & 3;          // B: half = wc>>1, sub-64 = wc&1

    f32x16 acc[4][2];              // [m-block 32][n-block 32] = 128 AGPR
#pragma unroll
    for (int i = 0; i < 4; ++i)
#pragma unroll
        for (int j = 0; j < 2; ++j)
            acc[i][j] = (f32x16)(0.0f);

    // ---- staging (identical to R16) ----
    const int cS = (t & 7) ^ ((t >> 3) & 7);
    const unsigned short* gA = Xh + (size_t)(bm0 + (t >> 3)) * K_DIM + cS * 8;
    const unsigned*       gB = Wt + (size_t)(bn0 + (t >> 3)) * KH + cS * 4;
    const int t8 = t * 8;

#define SU_A(buf, h, c, kt)                                                   \
    gld_lds16(gA + (size_t)((h) * 128 + (c) * 64) * K_DIM + (size_t)(kt) * 64, \
              &LA[buf][h][(c) * 4096 + t8])
#define SU_B(buf, bh, ch, kt)                                                 \
    gld_lds16(gB + (size_t)((bh) * 128 + (ch) * 64) * KH + (size_t)(kt) * 32, \
              &LB[buf][bh][(ch) * 4096 + t8])

    // ---- hoisted frag addresses ----
    // A frag (32x32x16): lane l -> row = l&31, k-slot = 2*ks + (l>>5),
    // swizzled slot = s ^ (row&7) = s ^ (l&7).  ks-step = XOR {0,32,64,96}.
    const int hi  = l >> 5;
    const int sw0 = (hi ^ (l & 7)) * 16;
    const int aoff = wr * 16384 + (l & 31) * 128 + sw0;
    const int boff = (wc >> 1) * 16384 + ((wc & 1) * 64 + (l & 31)) * 128 + sw0;
    const char* const baseA = (const char*)&LA[0][0][0];
    const char* const baseB = (const char*)&LB[0][0][0];
    const char* const pA[4] = { baseA + aoff, baseA + (aoff ^ 32),
                                baseA + (aoff ^ 64), baseA + (aoff ^ 96) };
    const char* const pB[4] = { baseB + boff, baseB + (boff ^ 32),
                                baseB + (boff ^ 64), baseB + (boff ^ 96) };

    f16x8 af01[2][4], af23[2][4], bf0[4], bf1[4];

#define READ_AF01(D) do {                                                     \
    _Pragma("unroll")                                                         \
    for (int ks = 0; ks < 4; ++ks) {                                          \
        af01[0][ks] = *(const f16x8*)(pA[ks] + ((D) * 32768 + 0 * 4096));     \
        af01[1][ks] = *(const f16x8*)(pA[ks] + ((D) * 32768 + 1 * 4096));     \
    }                                                                         \
} while (0)

#define READ_AF23(D) do {                                                     \
    _Pragma("unroll")                                                         \
    for (int ks = 0; ks < 4; ++ks) {                                          \
        af23[0][ks] = *(const f16x8*)(pA[ks] + ((D) * 32768 + 2 * 4096));     \
        af23[1][ks] = *(const f16x8*)(pA[ks] + ((D) * 32768 + 3 * 4096));     \
    }                                                                         \
} while (0)

#define READ_BF(D, nb, ARR) do {                                              \
    _Pragma("unroll")                                                         \
    for (int ks = 0; ks < 4; ++ks)                                            \
        ARR[ks] = *(const f16x8*)(pB[ks] + ((D) * 32768 + (nb) * 4096));      \
} while (0)

    // 8-MFMA cluster: 2 m-blocks x 1 n-block x 4 ks
#define Q8(AF, MB0, BF, NB) do {                                              \
    __builtin_amdgcn_s_setprio(1);                                            \
    _Pragma("unroll")                                                         \
    for (int ks = 0; ks < 4; ++ks) {                                          \
        acc[(MB0) + 0][NB] = __builtin_amdgcn_mfma_f32_32x32x16_f16(          \
            AF[0][ks], BF[ks], acc[(MB0) + 0][NB], 0, 0, 0);                  \
        acc[(MB0) + 1][NB] = __builtin_amdgcn_mfma_f32_32x32x16_f16(          \
            AF[1][ks], BF[ks], acc[(MB0) + 1][NB], 0, 0, 0);                  \
    }                                                                         \
    __builtin_amdgcn_s_setprio(0);                                            \
} while (0)

#define WAITV(n) asm volatile("s_waitcnt vmcnt(" #n ")" ::: "memory")
#define LGKM0()  do { asm volatile("s_waitcnt lgkmcnt(0)" ::: "memory");      \
                      __builtin_amdgcn_sched_barrier(0); } while (0)
#define BAR()    __builtin_amdgcn_s_barrier()

#define TILE_STD(D, DN, ktn) do {                                             \
    SU_B(DN, 0, 0, ktn); SU_B(DN, 0, 1, ktn);                                 \
    WAITV(4); BAR();                                                          \
    READ_AF01(D); READ_BF(D, 0, bf0); LGKM0();                                \
    Q8(af01, 0, bf0, 0);                                                      \
    SU_B(DN, 1, 0, ktn); SU_B(DN, 1, 1, ktn);                                 \
    READ_BF(D, 1, bf1); LGKM0();                                              \
    Q8(af01, 0, bf1, 1);                                                      \
    SU_A(DN, 0, 0, ktn); SU_A(DN, 1, 0, ktn);                                 \
    WAITV(6); BAR();                                                          \
    READ_AF23(D); LGKM0();                                                    \
    Q8(af23, 2, bf1, 1);                                                      \
    SU_A(DN, 0, 1, ktn); SU_A(DN, 1, 1, ktn);                                 \
    Q8(af23, 2, bf0, 0);                                                      \
} while (0)

#define TILE_LAST(D) do {                                                     \
    WAITV(2); BAR();                                                          \
    READ_AF01(D); READ_BF(D, 0, bf0); LGKM0();                                \
    Q8(af01, 0, bf0, 0);                                                      \
    READ_BF(D, 1, bf1); LGKM0();                                              \
    Q8(af01, 0, bf1, 1);                                                      \
    WAITV(0); BAR();                                                          \
    READ_AF23(D); LGKM0();                                                    \
    Q8(af23, 2, bf1, 1);                                                      \
    Q8(af23, 2, bf0, 0);                                                      \
} while (0)

    // prologue: tile 0 units in consumption order
    SU_B(0, 0, 0, 0); SU_B(0, 0, 1, 0); SU_B(0, 1, 0, 0); SU_B(0, 1, 1, 0);
    SU_A(0, 0, 0, 0); SU_A(0, 1, 0, 0); SU_A(0, 0, 1, 0); SU_A(0, 1, 1, 0);

    for (int i = 0; i < 31; ++i) {
        TILE_STD(0, 1, 2 * i + 1);        // tile 2i,   stages 2i+1
        TILE_STD(1, 0, 2 * i + 2);        // tile 2i+1, stages 2i+2
    }
    TILE_STD(0, 1, 63);                   // tile 62, stages 63
    TILE_LAST(1);                         // tile 63

    // ---- epilogue: C/D 32x32 layout (m74/m101): col=l&31,
    //      row = (reg&3) + 8*(reg>>2) + 4*(l>>5) ----
#pragma unroll
    for (int nb = 0; nb < 2; ++nb) {
        const int col = bn0 + wc * 64 + nb * 32 + (l & 31);
        const float s = WS[col];
#pragma unroll
        for (int mb = 0; mb < 4; ++mb) {
            const int rbase = bm0 + wr * 128 + mb * 32 + 4 * hi;
#pragma unroll
            for (int reg = 0; reg < 16; ++reg) {
                const int row = rbase + (reg & 3) + 8 * (reg >> 2);
                Out[(size_t)row * N_DIM + col] = acc[mb][nb][reg] * s;
            }
        }
    }
#undef SU_A
#undef SU_B
#undef READ_AF01
#undef READ_AF23
#undef READ_BF
#undef Q8
#undef WAITV
#undef LGKM0
#undef BAR
#undef TILE_STD
#undef TILE_LAST
}

extern "C" void kernel_launch(void* const* d_in, const int* in_sizes, int n_in,
                              void* d_out, int out_size, void* d_ws, size_t ws_size,
                              hipStream_t stream) {
    const float* X  = (const float*)d_in[0];
    const int*   WP = (const int*)d_in[1];
    const float* WS = (const float*)d_in[2];
    float*       Out = (float*)d_out;

    unsigned short* Xh = (unsigned short*)d_ws;
    unsigned*       Wt = (unsigned*)((char*)d_ws + WS_XH_BYTES);

    cvt_x_kernel<<<(M_DIM * K_DIM) / (256 * 8), 256, 0, stream>>>(X, Xh);
    dim3 gdq(N_DIM / 64, KH / 64);                    // 172 x 32
    dqt_kernel<<<gdq, 256, 0, stream>>>(WP, Wt);
    dim3 grid((N_DIM / 256) * (M_DIM / 256));         // 688
    qgemm10_kernel<<<grid, 512, 0, stream>>>(Xh, Wt, WS, Out);
}